// Round 1
// baseline (960.432 us; speedup 1.0000x reference)
//
#include <hip/hip_runtime.h>

#define BLOCK  256
#define ITEMS  16
#define CHUNK  (BLOCK * ITEMS)   // 4096 elements per block
#define NBATCH 8
#define MAXLEN 256000
#define CROW4  16                // float4 per 64-float row

// dsh padding: e + e/16 breaks the stride-16-int (64B/lane) pattern that put
// 64 lanes on 2 banks (32-way conflict) during rank assignment.
#define DSHI(e) ((e) + ((e) >> 4))
#define DSHSZ   (CHUNK + CHUNK / 16)

// ---- Kernel 1: per-block histogram of inds[:,0] + compact uint8 b-array ----
// hist already streams all of inds (32 MB); emitting the 2 MB uint8 side array
// here lets scatter avoid re-fetching inds entirely (-30 MB HBM).
__global__ __launch_bounds__(BLOCK) void hist_kernel(const int4* __restrict__ inds,
                                                     int n,
                                                     int* __restrict__ blockCounts,
                                                     unsigned char* __restrict__ bcomp) {
    int base = blockIdx.x * CHUNK;
    __shared__ int cnt[NBATCH];
    if (threadIdx.x < NBATCH) cnt[threadIdx.x] = 0;
    __syncthreads();

    // packed 8 x 8-bit per-thread counters (max 16 per field)
    unsigned long long p8 = 0;
#pragma unroll
    for (int k = 0; k < ITEMS; ++k) {
        int idx = base + k * BLOCK + threadIdx.x;   // coalesced int4 loads
        int b = 0xFF;                               // sentinel for tail pad
        if (idx < n) {
            b = inds[idx].x;
            p8 += 1ull << (8 * b);
        }
        bcomp[idx] = (unsigned char)b;              // consecutive bytes per wave
    }
    // expand to 2 x (4 x 16-bit) so a 64-lane sum (max 1024/field) can't overflow
    unsigned long long lo = 0, hi = 0;
#pragma unroll
    for (int j = 0; j < 4; ++j) {
        lo |= ((p8 >> (8 * j)) & 0xFFull) << (16 * j);
        hi |= ((p8 >> (8 * (j + 4))) & 0xFFull) << (16 * j);
    }
#pragma unroll
    for (int d = 1; d < 64; d <<= 1) {
        lo += __shfl_xor(lo, d, 64);
        hi += __shfl_xor(hi, d, 64);
    }
    int lane = threadIdx.x & 63;
    if (lane == 0) {
#pragma unroll
        for (int j = 0; j < 4; ++j) {
            atomicAdd(&cnt[j],     (int)((lo >> (16 * j)) & 0xFFFFull));
            atomicAdd(&cnt[j + 4], (int)((hi >> (16 * j)) & 0xFFFFull));
        }
    }
    __syncthreads();
    if (threadIdx.x < NBATCH)
        blockCounts[blockIdx.x * NBATCH + threadIdx.x] = cnt[threadIdx.x];
}

// -------- Kernel 2: exclusive scan over blocks, one wave per batch ----------
__global__ __launch_bounds__(512) void scan_kernel(const int* __restrict__ blockCounts,
                                                   int numBlocks,
                                                   int* __restrict__ blockOffsets,
                                                   int* __restrict__ totals) {
    int w = threadIdx.x >> 6;      // batch = wave id (8 waves)
    int lane = threadIdx.x & 63;
    int carry = 0;
    for (int c = 0; c < numBlocks; c += 64) {
        int i = c + lane;
        int v = (i < numBlocks) ? blockCounts[i * NBATCH + w] : 0;
        int x = v;
#pragma unroll
        for (int d = 1; d < 64; d <<= 1) {
            int y = __shfl_up(x, d, 64);
            if (lane >= d) x += y;
        }
        if (i < numBlocks) blockOffsets[i * NBATCH + w] = carry + x - v;
        carry += __shfl(x, 63, 64);
    }
    if (lane == 0) totals[w] = carry;
}

// -------- Kernel 3: rank + cooperative row scatter + tail zero (fused) ------
// LDS = 17.0K dsh + 9.0K off + small = ~26.2 KB -> 6 blocks/CU (was 41.3 KB,
// 3 blocks/CU). 24 waves/CU to hide the copy loop's HBM latency.
__global__ __launch_bounds__(BLOCK, 6) void scatter_kernel(const int4*  __restrict__ bcomp4,
                                                           const float4* __restrict__ feat,
                                                           const int*   __restrict__ blockOffsets,
                                                           const int*   __restrict__ totals,
                                                           float4* __restrict__ out) {
    __shared__ int dsh[DSHSZ];                 // dst row per element (17 KB, padded)
    __shared__ int off[BLOCK * 9];             // per-thread per-batch base (9 KB)
    __shared__ int boff[NBATCH];
    __shared__ unsigned long long wlo[4], whi[4];

    int tid = threadIdx.x;
    int base = blockIdx.x * CHUNK;
    if (tid < NBATCH) boff[tid] = blockOffsets[blockIdx.x * NBATCH + tid];

    // ONE coalesced 16B load gives this thread its 16 contiguous batch ids.
    // Keep them packed in 4 words (regs), extract with static indices only.
    int4 bv = bcomp4[blockIdx.x * BLOCK + tid];
    unsigned int w0 = (unsigned int)bv.x, w1 = (unsigned int)bv.y;
    unsigned int w2 = (unsigned int)bv.z, w3 = (unsigned int)bv.w;

    // per-thread counts of its 16 CONTIGUOUS elements (preserves stable order)
    unsigned long long p8 = 0;
#pragma unroll
    for (int q = 0; q < 4; ++q) {
        unsigned int w = (q == 0) ? w0 : (q == 1) ? w1 : (q == 2) ? w2 : w3;
#pragma unroll
        for (int j = 0; j < 4; ++j) {
            int b = (int)((w >> (8 * j)) & 0xFF);
            if (b != 0xFF) p8 += 1ull << (8 * b);
        }
    }
    unsigned long long lo = 0, hi = 0;
#pragma unroll
    for (int j = 0; j < 4; ++j) {
        lo |= ((p8 >> (8 * j)) & 0xFFull) << (16 * j);
        hi |= ((p8 >> (8 * (j + 4))) & 0xFFull) << (16 * j);
    }

    // 64-lane inclusive scan of packed 16-bit fields (block max 4096 < 65536)
    unsigned long long slo = lo, shi = hi;
    int lane = tid & 63, wave = tid >> 6;
#pragma unroll
    for (int d = 1; d < 64; d <<= 1) {
        unsigned long long tlo = __shfl_up(slo, d, 64);
        unsigned long long thi = __shfl_up(shi, d, 64);
        if (lane >= d) { slo += tlo; shi += thi; }
    }
    if (lane == 63) { wlo[wave] = slo; whi[wave] = shi; }
    __syncthreads();                             // covers boff + wlo/whi
    unsigned long long plo = slo - lo, phi = shi - hi;   // exclusive within wave
#pragma unroll
    for (int w = 0; w < 4; ++w)
        if (w < wave) { plo += wlo[w]; phi += whi[w]; }

    // per-thread per-batch starting rank (global): block offset + in-block exclusive
#pragma unroll
    for (int j = 0; j < 4; ++j) {
        off[tid * 9 + j]     = boff[j]     + (int)((plo >> (16 * j)) & 0xFFFF);
        off[tid * 9 + j + 4] = boff[j + 4] + (int)((phi >> (16 * j)) & 0xFFFF);
    }

    // assign destination rows in original order (byte j of word q = element s+4q+j)
    int s = tid * ITEMS;
#pragma unroll
    for (int q = 0; q < 4; ++q) {
        unsigned int w = (q == 0) ? w0 : (q == 1) ? w1 : (q == 2) ? w2 : w3;
#pragma unroll
        for (int j = 0; j < 4; ++j) {
            int e = s + 4 * q + j;
            int b = (int)((w >> (8 * j)) & 0xFF);
            if (b != 0xFF) {
                int r = off[tid * 9 + b]++;      // owner-thread LDS RMW, no races
                dsh[DSHI(e)] = (r < MAXLEN) ? (b * MAXLEN + r) : -1;
            } else {
                dsh[DSHI(e)] = -1;
            }
        }
    }
    __syncthreads();

    // cooperative copy: 16 lanes per row (16 x float4 = 256 B), 32 rows/iter,
    // two loads in flight before the stores (restrict makes the reorder legal).
    int lane16 = tid & 15;
    int rg = tid >> 4;                           // 0..15
    for (int r0 = 0; r0 < CHUNK; r0 += 32) {
        int e0 = r0 + rg, e1 = e0 + 16;
        int d0 = dsh[DSHI(e0)], d1 = dsh[DSHI(e1)];
        bool p0 = (d0 >= 0), p1 = (d1 >= 0);
        float4 v0, v1;
        if (p0) v0 = feat[(base + e0) * CROW4 + lane16];
        if (p1) v1 = feat[(base + e1) * CROW4 + lane16];
        if (p0) out[d0 * CROW4 + lane16] = v0;
        if (p1) out[d1 * CROW4 + lane16] = v1;
    }

    // fused tail zero: rows >= totals[b] are disjoint from every copy write
    float4 z = make_float4(0.f, 0.f, 0.f, 0.f);
#pragma unroll
    for (int b = 0; b < NBATCH; ++b) {
        int cnt = totals[b];
        if (cnt > MAXLEN) cnt = MAXLEN;
        int s4 = (b * MAXLEN + cnt) * CROW4;     // float4 units, fits in int
        int e4 = (b + 1) * MAXLEN * CROW4;
        for (int i = s4 + blockIdx.x * BLOCK + tid; i < e4; i += gridDim.x * BLOCK)
            out[i] = z;
    }
}

extern "C" void kernel_launch(void* const* d_in, const int* in_sizes, int n_in,
                              void* d_out, int out_size, void* d_ws, size_t ws_size,
                              hipStream_t stream) {
    const int4*   inds = (const int4*)d_in[0];
    const float4* feat = (const float4*)d_in[1];
    float4* out = (float4*)d_out;
    int n = in_sizes[0] / 4;                     // N = 2,000,000
    int numBlocks = (n + CHUNK - 1) / CHUNK;     // 489

    int* blockCounts  = (int*)d_ws;
    int* blockOffsets = blockCounts + numBlocks * NBATCH;
    int* totals       = blockOffsets + numBlocks * NBATCH;
    // byte offset of bcomp = (489*8*2 + 8)*4 = 31328, 16B-aligned for int4 loads
    unsigned char* bcomp = (unsigned char*)(totals + NBATCH);

    hist_kernel<<<numBlocks, BLOCK, 0, stream>>>(inds, n, blockCounts, bcomp);
    scan_kernel<<<1, 512, 0, stream>>>(blockCounts, numBlocks, blockOffsets, totals);
    scatter_kernel<<<numBlocks, BLOCK, 0, stream>>>((const int4*)bcomp, feat,
                                                    blockOffsets, totals, out);
}